// Round 1
// baseline (102.778 us; speedup 1.0000x reference)
//
#include <hip/hip_runtime.h>

#define WIRE_DIM  32
#define NUM_WIRES 64
#define BATCH     8192
#define HID       10

// broadcast-read a float from a wave-uniform lane index -> scalar
__device__ __forceinline__ float rl(float x, int slane) {
    return __uint_as_float(__builtin_amdgcn_readlane(__float_as_uint(x), slane));
}

__global__ __launch_bounds__(256, 5) void isnet_kernel(
    const float* __restrict__ outputs,
    const int*   __restrict__ tests,
    const float* __restrict__ W1,
    const float* __restrict__ bias1,
    const float* __restrict__ W2,
    const float* __restrict__ bias2,
    float*       __restrict__ out)
{
    // wave-private staging: 4 waves x 64 rows x 32 floats = 32 KB/block EXACT
    // (was 36 KB padded -> 4 blocks/CU; now 5 blocks/CU = 20 waves).
    // Bank conflicts handled by XOR swizzle instead of padding:
    //   LDS[row][chunk] = G[row][chunk ^ (row&7)]   (16B chunks, involution)
    // achieved by pre-swizzling the GLOBAL source address of global_load_lds
    // (m173 pattern: gload_lds writes linearly, so swizzle source + read, never dest).
    __shared__ __align__(16) float stage[4][NUM_WIRES * WIRE_DIM];

    const int tid  = threadIdx.x;
    const int lane = tid & 63;
    const int wave = __builtin_amdgcn_readfirstlane(tid >> 6); // wave-uniform SGPR
    float* buf = stage[wave];

    const int b = blockIdx.x * 4 + wave;          // one batch per wave

    const int sp = __builtin_amdgcn_readfirstlane(tests[2 * b]);      // person
    const int sl = __builtin_amdgcn_readfirstlane(tests[2 * b + 1]);  // location

    const int d  = lane & 31;
    const int h0 = (lane >> 5) * 5;

    const float* gb = outputs + (size_t)b * (NUM_WIRES * WIRE_DIM);

    // ---- EARLY independent loads: person element DIRECT from global ----
    // (breaks the serial stage->LDS->reduce dependency; 128B coalesced,
    //  same cachelines the staging fetches anyway)
    const float pd = gb[sp * WIRE_DIM + d];
    float wp5[5];
    #pragma unroll
    for (int k = 0; k < 5; ++k) wp5[k] = W1[d * HID + h0 + k];

    // ---- stage 8KB batch row-block: 8 x global_load_lds dwordx4 ----
    // instruction t covers rows 8t..8t+7; lane: r=lane>>3 (row in slab),
    // c=lane&7 (16B chunk). source chunk pre-swizzled: c ^ r  ( (8t+r)&7 == r )
    {
        const int r = lane >> 3;
        const int c = lane & 7;
        const float* gs = gb + r * WIRE_DIM + ((c ^ r) << 2);
        #pragma unroll
        for (int t = 0; t < 8; ++t) {
            __builtin_amdgcn_global_load_lds(
                (const __attribute__((address_space(1))) float*)(gs + t * 256),
                (__attribute__((address_space(3))) float*)(buf + t * 256),
                16, 0, 0);
        }
    }

    // ---- cooperative person projection overlapping the staging flight ----
    // pacc[h] = sum_d person[d]*W1[d][h]; lane l owns d=l&31, h-group 5*(l>>5)
    float pc[5];
    #pragma unroll
    for (int k = 0; k < 5; ++k) pc[k] = pd * wp5[k];
    #pragma unroll
    for (int off = 16; off > 0; off >>= 1)
        #pragma unroll
        for (int k = 0; k < 5; ++k) pc[k] += __shfl_xor(pc[k], off);
    // half 0 lanes hold pacc[0..4], half 1 lanes hold pacc[5..9] -> SGPRs
    float pacc[HID];
    #pragma unroll
    for (int k = 0; k < 5; ++k) {
        pacc[k]     = rl(pc[k], 0);
        pacc[5 + k] = rl(pc[k], 32);
    }

    // ---- drain staging (wave-private buffer: no __syncthreads needed) ----
    asm volatile("s_waitcnt vmcnt(0)" ::: "memory");
    __builtin_amdgcn_sched_barrier(0);   // keep ds_reads below the wait (rule #18)

    // ---- own wire row -> registers, swizzled read: chunk t ^ (row&7) ----
    // banks: first dword = 4*(t^(lane&7)) mod 32 -> 2 lanes/bank per phase (free)
    float4 x[8];
    #pragma unroll
    for (int t = 0; t < 8; ++t)
        x[t] = *(const float4*)&buf[lane * WIRE_DIM + ((t ^ (lane & 7)) << 2)];

    float acc[HID];
    #pragma unroll
    for (int h = 0; h < HID; ++h) acc[h] = bias1[h] + pacc[h];

    // ---- wire half only: 320 FMAs, weights uniform -> s_load ----
    #pragma unroll
    for (int j = 0; j < 8; ++j) {
        const float* ww = W1 + (32 + 4 * j) * HID;   // wire rows 32+4j..
        #pragma unroll
        for (int h = 0; h < HID; ++h) {
            acc[h] += x[j].x * ww[0 * HID + h] + x[j].y * ww[1 * HID + h]
                    + x[j].z * ww[2 * HID + h] + x[j].w * ww[3 * HID + h];
        }
    }

    // ---- relu -> W2 -> logit per lane(=wire) -> wave softmax -> loss ----
    float v = bias2[0];
    #pragma unroll
    for (int h = 0; h < HID; ++h) v += fmaxf(acc[h], 0.f) * W2[h];

    float m = v;
    #pragma unroll
    for (int off = 32; off > 0; off >>= 1) m = fmaxf(m, __shfl_xor(m, off));
    float s = __expf(v - m);
    #pragma unroll
    for (int off = 32; off > 0; off >>= 1) s += __shfl_xor(s, off);
    float lv = rl(v, sl);                        // logit at `location`
    if (lane == 0) out[b] = m + __logf(s) - lv;  // -log_softmax[loc]
}

extern "C" void kernel_launch(void* const* d_in, const int* in_sizes, int n_in,
                              void* d_out, int out_size, void* d_ws, size_t ws_size,
                              hipStream_t stream) {
    const float* outputs = (const float*)d_in[0];
    const int*   tests   = (const int*)d_in[1];
    const float* W1      = (const float*)d_in[2];
    const float* b1      = (const float*)d_in[3];
    const float* W2      = (const float*)d_in[4];
    const float* b2      = (const float*)d_in[5];
    float* out = (float*)d_out;

    // 4 batches per block (4 waves x 1 batch) -> 2048 blocks
    isnet_kernel<<<BATCH / 4, 256, 0, stream>>>(
        outputs, tests, W1, b1, W2, b2, out);
}

// Round 3
// 102.568 us; speedup vs baseline: 1.0020x; 1.0020x over previous
//
#include <hip/hip_runtime.h>

#define WIRE_DIM  32
#define NUM_WIRES 64
#define BATCH     8192
#define HID       10

// broadcast-read a float from a wave-uniform lane index -> scalar
__device__ __forceinline__ float rl(float x, int slane) {
    return __uint_as_float(__builtin_amdgcn_readlane(__float_as_uint(x), slane));
}

__global__ __launch_bounds__(256, 5) void isnet_kernel(
    const float* __restrict__ outputs,
    const int*   __restrict__ tests,
    const float* __restrict__ W1,
    const float* __restrict__ bias1,
    const float* __restrict__ W2,
    const float* __restrict__ bias2,
    float*       __restrict__ out)
{
    // wave-private staging: 4 waves x 64 rows x 32 floats = 32 KB/block EXACT
    // -> 5 blocks/CU (LDS-limited), 20 waves/CU.
    // Bank-conflict-free via XOR swizzle (verified absmax=0 in R1):
    //   LDS[row][chunk] = G[row][chunk ^ (row&7)]   (16B chunks, involution)
    // realized by pre-swizzling the GLOBAL source of global_load_lds
    // (gload_lds dest must stay linear, m104/m173).
    __shared__ __align__(16) float stage[4][NUM_WIRES * WIRE_DIM];

    const int tid  = threadIdx.x;
    const int lane = tid & 63;
    const int wave = __builtin_amdgcn_readfirstlane(tid >> 6);
    float* buf = stage[wave];

    const int b = blockIdx.x * 4 + wave;          // one batch per wave
    const float* gb = outputs + (size_t)b * (NUM_WIRES * WIRE_DIM);

    // ================= PHASE 1: issue staging FIRST =================
    // R0/R1 bug: tests-load + readfirstlane forced a ~900cy vmcnt drain
    // BEFORE the 8 staging loads issued -> per-wave front bubble, BW ~57%.
    // These 8 loads depend only on blockIdx/tid: put them first, pin order.
    {
        const int r = lane >> 3;                  // row within 8-row slab
        const int c = lane & 7;                   // 16B chunk within row
        const float* gs = gb + r * WIRE_DIM + ((c ^ r) << 2);
        #pragma unroll
        for (int t = 0; t < 8; ++t) {
            __builtin_amdgcn_global_load_lds(
                (const __attribute__((address_space(1))) float*)(gs + t * 256),
                (__attribute__((address_space(3))) float*)(buf + t * 256),
                16, 0, 0);
        }
    }
    __builtin_amdgcn_sched_barrier(0);  // nothing hoists above the staging issue

    // ================= PHASE 2: independent small loads =================
    const int2 tt = *(const int2*)(tests + 2 * b);   // (person, location)

    const int d  = lane & 31;
    const int h0 = (lane >> 5) * 5;
    float wp5[5];
    #pragma unroll
    for (int k = 0; k < 5; ++k) wp5[k] = W1[d * HID + h0 + k];  // 2.5KB, L2-hot

    // ================= PHASE 3: single drain, then LDS-only =================
    asm volatile("s_waitcnt vmcnt(0)" ::: "memory");
    __builtin_amdgcn_sched_barrier(0);   // rule #18: no LDS use hoists above

    const int sp = __builtin_amdgcn_readfirstlane(tt.x);   // person
    const int sl = __builtin_amdgcn_readfirstlane(tt.y);   // location

    // person element from the staged (swizzled) buffer:
    // element d of row sp lives at chunk (d>>2)^(sp&7), sub-dword d&3
    const float pd = buf[sp * WIRE_DIM + ((((d >> 2) ^ (sp & 7)) << 2) | (d & 3))];

    // cooperative person projection: pacc[h] = sum_d person[d]*W1[d][h]
    // lane l owns d=l&31, h-group 5*(l>>5); butterfly; broadcast via readlane
    float pc[5];
    #pragma unroll
    for (int k = 0; k < 5; ++k) pc[k] = pd * wp5[k];
    #pragma unroll
    for (int off = 16; off > 0; off >>= 1)
        #pragma unroll
        for (int k = 0; k < 5; ++k) pc[k] += __shfl_xor(pc[k], off);
    float pacc[HID];
    #pragma unroll
    for (int k = 0; k < 5; ++k) {
        pacc[k]     = rl(pc[k], 0);
        pacc[5 + k] = rl(pc[k], 32);
    }

    // own wire row -> registers, swizzled read: chunk t ^ (lane&7)
    // first dword bank = 4*(t^(lane&7)) mod 32 -> 2 lanes/bank (free, m136)
    float4 x[8];
    #pragma unroll
    for (int t = 0; t < 8; ++t)
        x[t] = *(const float4*)&buf[lane * WIRE_DIM + ((t ^ (lane & 7)) << 2)];

    float acc[HID];
    #pragma unroll
    for (int h = 0; h < HID; ++h) acc[h] = bias1[h] + pacc[h];

    // wire half only: 320 FMAs/lane, weights wave-uniform -> s_load'd
    #pragma unroll
    for (int j = 0; j < 8; ++j) {
        const float* ww = W1 + (32 + 4 * j) * HID;   // wire rows 32+4j..
        #pragma unroll
        for (int h = 0; h < HID; ++h) {
            acc[h] += x[j].x * ww[0 * HID + h] + x[j].y * ww[1 * HID + h]
                    + x[j].z * ww[2 * HID + h] + x[j].w * ww[3 * HID + h];
        }
    }

    // relu -> W2 -> logit per lane(=wire) -> wave softmax -> loss
    float v = bias2[0];
    #pragma unroll
    for (int h = 0; h < HID; ++h) v += fmaxf(acc[h], 0.f) * W2[h];

    float m = v;
    #pragma unroll
    for (int off = 32; off > 0; off >>= 1) m = fmaxf(m, __shfl_xor(m, off));
    float s = __expf(v - m);
    #pragma unroll
    for (int off = 32; off > 0; off >>= 1) s += __shfl_xor(s, off);
    float lv = rl(v, sl);                        // logit at `location`
    if (lane == 0) out[b] = m + __logf(s) - lv;  // -log_softmax[loc]
}

extern "C" void kernel_launch(void* const* d_in, const int* in_sizes, int n_in,
                              void* d_out, int out_size, void* d_ws, size_t ws_size,
                              hipStream_t stream) {
    const float* outputs = (const float*)d_in[0];
    const int*   tests   = (const int*)d_in[1];
    const float* W1      = (const float*)d_in[2];
    const float* b1      = (const float*)d_in[3];
    const float* W2      = (const float*)d_in[4];
    const float* b2      = (const float*)d_in[5];
    float* out = (float*)d_out;

    // 4 batches per block (4 waves x 1 batch) -> 2048 blocks
    isnet_kernel<<<BATCH / 4, 256, 0, stream>>>(
        outputs, tests, W1, b1, W2, b2, out);
}